// Round 9
// baseline (412.523 us; speedup 1.0000x reference)
//
#include <hip/hip_runtime.h>

// Pipeline: cvt(x,Wqkv,Wproj)->bf16 | bias_pre bf16 [16][257][288] pair-packed |
//           gemm_qkv (bf16 MFMA; q*(0.125*log2e)+qb, k, v+vb -> v^T layout) |
//           attn_fused (S=QK^T with bias-in-C, log2-softmax, O=PV, defer norm) |
//           gemm_proj (+proj_bias, fp32 out)
// R13 per-kernel GEMM cores (R12 counters attributed: dbuf helped proj
// ~-18us [B=2MB L2-resident -> latency covered] but hurt qkv +7us [B=6.3MB
// LLC-latency, uncoverable by 320cyc compute + 2x barriers]):
//   gemm_qkv : R8 core — BK=64, 32KB LDS, 2 barriers/iter (measured 153us).
//   gemm_proj: R12 core — BK=32 static double-buffer, stage-before-compute.
// attn R13: T14 async reg-prefetch. The 6 K/V chunk stagings each paid an
// exposed ~600-800cyc LLC round trip inside barrier pairs (per-block
// critical path ~6000cyc vs 360cyc MFMA floor). Now: double-buffered reg
// staging (kva/kvb, 3x bf16x8 each) — chunk ck+1 loads issue right after
// chunk ck's LDS write, hiding under barrier+MFMA(ck); K0 issues at kernel
// top (hides under bias init), V0 at QK chunk 2 (hides under softmax).
// Same barrier count/LDS; addressing identical.
// Kept: R7 v^T transpose epilogue; R8 tail-clamp removal; R11 bf16 bias
// pack + qt4 wave-0 gating + attn XCD relabel. GEMM XCD swizzle: falsified
// twice (LLC-resident) — absent.

typedef unsigned short u16;
typedef __attribute__((ext_vector_type(8))) short bf16x8;
typedef __attribute__((ext_vector_type(4))) float f32x4;

#define MFMA16(a, b, c) __builtin_amdgcn_mfma_f32_16x16x32_bf16(a, b, c, 0, 0, 0)
#define GLDS16(g, l)                                                           \
  __builtin_amdgcn_global_load_lds(                                            \
      (const __attribute__((address_space(1))) void*)(g),                      \
      (__attribute__((address_space(3))) void*)(l), 16, 0, 0)

// element offsets within qkv buffer
#define QOFF 0
#define KOFF 16842752
#define VTOFF 33685504
#define VTP 264  // v^T row pitch (elems), 528 B = 33*16

__device__ __forceinline__ u16 f2bf(float f) {
  unsigned u = __builtin_bit_cast(unsigned, f);
  u += 0x7FFFu + ((u >> 16) & 1u);  // RNE; inputs are finite
  return (u16)(u >> 16);
}
__device__ __forceinline__ unsigned pack2(float a, float b) {
  return (unsigned)f2bf(a) | ((unsigned)f2bf(b) << 16);
}

// ---------------- fp32 -> bf16 convert (vectorized) ----------------
__global__ __launch_bounds__(256) void cvt_bf16(const float* __restrict__ in,
                                                u16* __restrict__ out, int n4) {
  int i = blockIdx.x * 256 + threadIdx.x;
  if (i < n4) {
    float4 v = ((const float4*)in)[i];
    uint2 o;
    o.x = pack2(v.x, v.y);
    o.y = pack2(v.z, v.w);
    ((uint2*)out)[i] = o;
  }
}

// ---- bias precompute: bf16 [16][257][288] pair-interleaved (x log2e) ----
// entry (h,i,j) at h*74016 + i*288 + (j>>5)*32 + (j&15)*2 + ((j>>4)&1);
// cols 257..287 prefilled with bf16(-3e38) so the attn init needs no branch.
__global__ __launch_bounds__(256) void bias_pre(const float* __restrict__ tab,
                                                const int* __restrict__ idx,
                                                u16* __restrict__ out) {
  int t = blockIdx.x * 256 + threadIdx.x;
  if (t < 66049) {
    int i = t / 257, j = t - i * 257;
    int off = i * 288 + ((j >> 5) << 5) + ((j & 15) << 1) + ((j >> 4) & 1);
    int id = idx[t];
    const float* row = tab + (size_t)id * 16;
#pragma unroll
    for (int h = 0; h < 16; h++)
      out[(size_t)h * 74016 + off] = f2bf(row[h] * 1.4426950408889634f);
  } else if (t < 66049 + 257 * 31) {
    int u = t - 66049;
    int i = u / 31, j = 257 + (u - i * 31);
    int off = i * 288 + ((j >> 5) << 5) + ((j & 15) << 1) + ((j >> 4) & 1);
#pragma unroll
    for (int h = 0; h < 16; h++)
      out[(size_t)h * 74016 + off] = 0xFF7Fu;  // bf16 ~ -3.39e38
  }
}

// ---------------- GEMM core A: BK=64, 2 barriers/iter (for gemm_qkv) ----
// 128x128 tile, 256 thr (4 waves 2x2 of 64x64), 16x16x32 MFMA.
// LDS row = 64 elems (8 slots of 16B); k-group G of row r at slot G^(r&7).
#define GEMM_PROLOG64(M_, K_)                                                  \
  __shared__ __align__(16) u16 SMEM[16384];                                    \
  const int M = (M_), K = (K_);                                                \
  const int tid = threadIdx.x;                                                 \
  const int lane = tid & 63, wave = tid >> 6;                                  \
  const int quad = lane >> 4, l15 = lane & 15;                                 \
  const int wr = (wave >> 1) * 64, wc = (wave & 1) * 64;                       \
  const int m0 = blockIdx.y * 128, n0 = blockIdx.x * 128;                      \
  const int sgk = ((tid & 7) ^ ((tid >> 3) & 7)) * 8;                          \
  const int fo0 = (quad ^ (l15 & 7)) * 8;                                      \
  const int fo1 = ((4 + quad) ^ (l15 & 7)) * 8;                                \
  const u16* pa0 = A + (size_t)(m0 + (tid >> 3)) * K + sgk;                    \
  const u16* pb0 = B + (size_t)(n0 + (tid >> 3)) * K + sgk;                    \
  f32x4 acc[4][4];                                                             \
  _Pragma("unroll") for (int i = 0; i < 4; i++)                                \
  _Pragma("unroll") for (int j = 0; j < 4; j++)                                \
      acc[i][j] = (f32x4){0.f, 0.f, 0.f, 0.f};                                 \
  for (int k0 = 0; k0 < K; k0 += 64) {                                         \
    __syncthreads();                                                           \
    _Pragma("unroll") for (int b = 0; b < 4; b++) {                            \
      GLDS16(pa0 + k0 + (size_t)b * 32 * K, SMEM + b * 2048 + tid * 8);        \
      GLDS16(pb0 + k0 + (size_t)b * 32 * K, SMEM + 8192 + b * 2048 + tid * 8); \
    }                                                                          \
    __syncthreads();                                                           \
    _Pragma("unroll") for (int kk = 0; kk < 2; kk++) {                         \
      const int fo = kk ? fo1 : fo0;                                           \
      bf16x8 bfr[4];                                                           \
      _Pragma("unroll") for (int t = 0; t < 4; t++)                            \
          bfr[t] = *(const bf16x8*)(SMEM + 8192 + (wc + t * 16 + l15) * 64 + fo); \
      _Pragma("unroll") for (int i = 0; i < 4; i++) {                          \
        bf16x8 afr = *(const bf16x8*)(SMEM + (wr + i * 16 + l15) * 64 + fo);   \
        _Pragma("unroll") for (int j = 0; j < 4; j++)                          \
            acc[i][j] = MFMA16(afr, bfr[j], acc[i][j]);                        \
      }                                                                        \
    }                                                                          \
  }

// ---------------- GEMM core B: BK=32 static double-buffer (for gemm_proj) --
// LDS row = 32 elems; 16B-group g of row r at slot g^((r>>1)&3).
#define GSTAGE(BO, TI)                                                         \
  GLDS16(pa0 + (TI) * 32, SMEM + (BO) + tid * 8);                              \
  GLDS16(pa1 + (TI) * 32, SMEM + (BO) + 2048 + tid * 8);                       \
  GLDS16(pb0 + (TI) * 32, SMEM + (BO) + 4096 + tid * 8);                       \
  GLDS16(pb1 + (TI) * 32, SMEM + (BO) + 6144 + tid * 8);

#define GCOMPUTE(BO)                                                           \
  {                                                                            \
    const u16* As_ = SMEM + (BO);                                              \
    const u16* Bs_ = SMEM + (BO) + 4096;                                       \
    bf16x8 bfr[4];                                                             \
    _Pragma("unroll") for (int t = 0; t < 4; t++)                              \
        bfr[t] = *(const bf16x8*)(Bs_ + (wc + t * 16 + l15) * 32 + fo);        \
    _Pragma("unroll") for (int i = 0; i < 4; i++) {                            \
      bf16x8 afr = *(const bf16x8*)(As_ + (wr + i * 16 + l15) * 32 + fo);      \
      _Pragma("unroll") for (int j = 0; j < 4; j++)                            \
          acc[i][j] = MFMA16(afr, bfr[j], acc[i][j]);                          \
    }                                                                          \
  }

#define GEMM_PROLOG_DB(M_, K_)                                                 \
  __shared__ __align__(16) u16 SMEM[16384];                                    \
  const int M = (M_), K = (K_);                                                \
  const int tid = threadIdx.x;                                                 \
  const int lane = tid & 63, wave = tid >> 6;                                  \
  const int quad = lane >> 4, l15 = lane & 15;                                 \
  const int wr = (wave >> 1) * 64, wc = (wave & 1) * 64;                       \
  const int m0 = blockIdx.y * 128, n0 = blockIdx.x * 128;                      \
  const int sgk = (((tid & 3) ^ ((tid >> 3) & 3))) * 8;                        \
  const int fo = ((quad ^ ((l15 >> 1) & 3))) * 8;                              \
  const u16* pa0 = A + (size_t)(m0 + (tid >> 2)) * K + sgk;                    \
  const u16* pa1 = pa0 + (size_t)64 * K;                                       \
  const u16* pb0 = B + (size_t)(n0 + (tid >> 2)) * K + sgk;                    \
  const u16* pb1 = pb0 + (size_t)64 * K;                                       \
  f32x4 acc[4][4];                                                             \
  _Pragma("unroll") for (int i = 0; i < 4; i++)                                \
  _Pragma("unroll") for (int j = 0; j < 4; j++)                                \
      acc[i][j] = (f32x4){0.f, 0.f, 0.f, 0.f};                                 \
  GSTAGE(0, 0)                                                                 \
  __syncthreads();                                                             \
  for (int kt = 0; kt < 30; kt += 2) {                                         \
    GSTAGE(8192, kt + 1)                                                       \
    GCOMPUTE(0)                                                                \
    __syncthreads();                                                           \
    GSTAGE(0, kt + 2)                                                          \
    GCOMPUTE(8192)                                                             \
    __syncthreads();                                                           \
  }                                                                            \
  GSTAGE(8192, 31)                                                             \
  GCOMPUTE(0)                                                                  \
  __syncthreads();                                                             \
  GCOMPUTE(8192)

// QKV GEMM: cols [q|k|v]; q,k -> [B][H][257][64]; v -> v^T [B][H][64][VTP].
__global__ __launch_bounds__(256, 4) void gemm_qkv(
    const u16* __restrict__ A, const u16* __restrict__ B,
    const float* __restrict__ qbias, const float* __restrict__ vbias,
    u16* __restrict__ C) {
  GEMM_PROLOG64(16448, 1024)
  if (n0 >= 2048) {
    // ---- v-tile epilogue: transpose via LDS, stores coalesced along nn ----
    u16* const T = SMEM;  // [64 col][128 row] u16, row index XOR-swizzled
    for (int p = 0; p < 2; p++) {
      __syncthreads();
      if ((wave & 1) == p) {
#pragma unroll
        for (int j = 0; j < 4; j++) {
          int cl = j * 16 + l15;
          int rem = (n0 + wc + j * 16 + l15) & 1023;
          float vb_ = vbias[rem];
          int swz = (cl & 15) << 3;  // flips row bits 3..6, keeps pairs
#pragma unroll
          for (int i = 0; i < 4; i++) {
            int rlb = wr + i * 16 + quad * 4;  // even
#pragma unroll
            for (int rr = 0; rr < 2; rr++) {
              unsigned pk = pack2(acc[i][j][rr * 2] + vb_,
                                  acc[i][j][rr * 2 + 1] + vb_);
              *(unsigned*)(T + cl * 128 + ((rlb + rr * 2) ^ swz)) = pk;
            }
          }
        }
      }
      __syncthreads();
      // store: wave w covers cols {w, w+4, ..., w+60}; lanes run along rows
#pragma unroll
      for (int cc = 0; cc < 16; cc++) {
        int cl = cc * 4 + wave;
        int rem = (n0 + p * 64 + cl) & 1023;
        int h = rem >> 6, d = rem & 63;
        size_t cb = (size_t)VTOFF + ((size_t)h * 64 + d) * VTP;
        int swz = (cl & 15) << 3;
#pragma unroll
        for (int half = 0; half < 2; half++) {
          int rl = half * 64 + lane;
          u16 val = T[cl * 128 + (rl ^ swz)];
          int m = m0 + rl;
          if (m < M) {
            unsigned bb2 = (unsigned)m / 257u;
            unsigned nn2 = (unsigned)m - bb2 * 257u;
            C[cb + (size_t)bb2 * (16 * 64 * VTP) + nn2] = val;
          }
        }
      }
    }
  } else {
    // ---- q/k epilogue (coalesced along d already) ----
#pragma unroll
    for (int i = 0; i < 4; i++) {
#pragma unroll
      for (int r = 0; r < 4; r++) {
        int row = m0 + wr + i * 16 + quad * 4 + r;
        if (row < M) {
          unsigned bb = (unsigned)row / 257u;
          unsigned nn = (unsigned)row - bb * 257u;
#pragma unroll
          for (int j = 0; j < 4; j++) {
            int c = n0 + wc + j * 16 + l15;
            int which = c >> 10, rem = c & 1023;
            float bias = (which == 0) ? qbias[rem] : 0.f;
            float v = acc[i][j][r] + bias;
            if (which == 0) v *= 0.18033688011112042f;  // 64^-0.5 * log2(e)
            int h = rem >> 6, d = rem & 63;
            size_t dst = (size_t)which * 16842752 +
                         (size_t)(bb * 16 + h) * 16448 + (size_t)nn * 64 + d;
            C[dst] = f2bf(v);
          }
        }
      }
    }
  }
}

// Proj GEMM: fp32 out + proj_bias, row-major [16448][1024].
__global__ __launch_bounds__(256, 4) void gemm_proj(
    const u16* __restrict__ A, const u16* __restrict__ B,
    const float* __restrict__ pbias, float* __restrict__ C) {
  GEMM_PROLOG_DB(16448, 1024)
#pragma unroll
  for (int i = 0; i < 4; i++) {
#pragma unroll
    for (int r = 0; r < 4; r++) {
      int row = m0 + wr + i * 16 + quad * 4 + r;
      if (row < M) {
#pragma unroll
        for (int j = 0; j < 4; j++) {
          int c = n0 + wc + j * 16 + l15;
          C[(size_t)row * 1024 + c] = acc[i][j][r] + pbias[c];
        }
      }
    }
  }
}

// ---------------- fused attention ----------------
// grid = B*H*5; block = 4 waves; wave owns 16 q-rows. Keys padded 257->288.
// T14 reg-prefetch: kva/kvb double-buffer (3x bf16x8 each); chunk ck+1's
// global loads issue right after chunk ck's LDS write -> latency hides
// under barrier+MFMA(ck). K0 at kernel top; V0 issued at QK chunk 2.
#define KLOAD(d0, d1, d2, CK)                                                  \
  {                                                                            \
    int gr0 = (CK) * 96 + r0;                                                  \
    d0 = (gr0 < 257) ? *(const bf16x8*)(kg + (size_t)gr0 * 64 + c0) : zv;      \
    d1 = (gr0 + 32 < 257) ? *(const bf16x8*)(kg + (size_t)(gr0 + 32) * 64 + c0) : zv; \
    d2 = (gr0 + 64 < 257) ? *(const bf16x8*)(kg + (size_t)(gr0 + 64) * 64 + c0) : zv; \
  }
#define KWRITE(s0, s1, s2)                                                     \
  {                                                                            \
    *(bf16x8*)(KVs + r0 * 72 + c0) = s0;                                       \
    *(bf16x8*)(KVs + (r0 + 32) * 72 + c0) = s1;                                \
    *(bf16x8*)(KVs + (r0 + 64) * 72 + c0) = s2;                                \
  }
#define VLOAD(d0, d1, d2, CK)                                                  \
  {                                                                            \
    d0 = *(const bf16x8*)(vtg + (size_t)vr0 * VTP + (CK) * 96 + vc0);          \
    d1 = *(const bf16x8*)(vtg + (size_t)vr1 * VTP + (CK) * 96 + vc1);          \
    d2 = *(const bf16x8*)(vtg + (size_t)vr2 * VTP + (CK) * 96 + vc2);          \
  }
#define VWRITE(s0, s1, s2)                                                     \
  {                                                                            \
    *(bf16x8*)(KVs + vr0 * 104 + vc0) = s0;                                    \
    *(bf16x8*)(KVs + vr1 * 104 + vc1) = s1;                                    \
    *(bf16x8*)(KVs + vr2 * 104 + vc2) = s2;                                    \
  }
#define QKMFMA(CK)                                                             \
  if (act) {                                                                   \
    _Pragma("unroll") for (int nt = 0; nt < 6; nt++) {                         \
      bf16x8 b0 = *(const bf16x8*)(KVs + (nt * 16 + l15) * 72 + quad * 8);     \
      bf16x8 b1 = *(const bf16x8*)(KVs + (nt * 16 + l15) * 72 + 32 + quad * 8);\
      int t = (CK) * 6 + nt;                                                   \
      s[t] = MFMA16(aq0, b0, s[t]);                                            \
      s[t] = MFMA16(aq1, b1, s[t]);                                            \
    }                                                                          \
  }
#define PWRITE(CK)                                                             \
  if (act) {                                                                   \
    _Pragma("unroll") for (int nt = 0; nt < 6; nt++) {                         \
      int t = (CK) * 6 + nt;                                                   \
      _Pragma("unroll") for (int r = 0; r < 4; r++)                            \
          Pw[(quad * 4 + r) * 104 + nt * 16 + l15] = f2bf(s[t][r]);            \
    }                                                                          \
  }
#define PVMFMA                                                                 \
  if (act) {                                                                   \
    _Pragma("unroll") for (int ks = 0; ks < 3; ks++) {                         \
      bf16x8 ap = *(const bf16x8*)(Pw + l15 * 104 + ks * 32 + quad * 8);       \
      _Pragma("unroll") for (int nt = 0; nt < 4; nt++) {                       \
        bf16x8 bv =                                                            \
            *(const bf16x8*)(KVs + (nt * 16 + l15) * 104 + ks * 32 + quad * 8);\
        o[nt] = MFMA16(ap, bv, o[nt]);                                         \
      }                                                                        \
    }                                                                          \
  }

__global__ __launch_bounds__(256, 3) void attn_fused(
    const u16* __restrict__ qkv, const u16* __restrict__ biasT,
    u16* __restrict__ out) {
  __shared__ __align__(16) u16 KVs[96 * 72];
  __shared__ __align__(16) u16 Ps[4 * 16 * 104];
  const int bx = blockIdx.x;
  const int xj = bx & 7, xi = bx >> 3;  // 640 per XCD
  const int qt = xi % 5;
  const int bh = (xi / 5) * 8 + xj;     // bijective: (xi/5, xj) <-> bh
  const int b = bh >> 4, h = bh & 15;
  const int tid = threadIdx.x, lane = tid & 63, wave = tid >> 6;
  const int quad = lane >> 4, l15 = lane & 15;
  const bool act = (qt < 4) || (wave == 0);  // wave-uniform compute gate
  const u16* qg = qkv + QOFF + (size_t)bh * 16448;
  const u16* kg = qkv + KOFF + (size_t)bh * 16448;
  const u16* vtg = qkv + VTOFF + (size_t)bh * (64 * VTP);

  // staging-thread coordinates (K: 8 threads/row; V^T: 12 groups/row)
  const int r0 = tid >> 3, c0 = (tid & 7) * 8;
  const int vr0 = tid / 12, vc0 = (tid % 12) * 8;
  const int vr1 = (256 + tid) / 12, vc1 = ((256 + tid) % 12) * 8;
  const int vr2 = (512 + tid) / 12, vc2 = ((512 + tid) % 12) * 8;
  const bf16x8 zv = {0, 0, 0, 0, 0, 0, 0, 0};

  bf16x8 kva0, kva1, kva2, kvb0, kvb1, kvb2;
  KLOAD(kva0, kva1, kva2, 0)  // K chunk 0 in flight under bias init

  // Q fragments straight from global (rows clamped for the tail tile)
  int qra = qt * 64 + wave * 16 + l15;
  if (qra > 256) qra = 256;
  const bf16x8 aq0 = *(const bf16x8*)(qg + (size_t)qra * 64 + quad * 8);
  const bf16x8 aq1 = *(const bf16x8*)(qg + (size_t)qra * 64 + 32 + quad * 8);

  // bias -> accumulator init (C-layout): bf16 pair-packed rows, pads = -3e38
  const int qbase = qt * 64 + wave * 16 + quad * 4;
  f32x4 s[18];
  if (act) {
    const u16* bb = biasT + (size_t)h * 74016;
#pragma unroll
    for (int r = 0; r < 4; r++) {
      int qr = qbase + r;
      if (qr > 256) qr = 256;
      const unsigned* brow = (const unsigned*)(bb + (size_t)qr * 288);
#pragma unroll
      for (int p = 0; p < 9; p++) {
        unsigned u = brow[p * 16 + l15];
        s[2 * p][r] = __builtin_bit_cast(float, u << 16);
        s[2 * p + 1][r] = __builtin_bit_cast(float, u & 0xFFFF0000u);
      }
    }
  }

  // Phase 1: S += Q.K^T over 3 key chunks of 96 (reg-prefetch pipelined)
  __syncthreads();
  KWRITE(kva0, kva1, kva2)
  KLOAD(kvb0, kvb1, kvb2, 1)
  __syncthreads();
  QKMFMA(0)
  __syncthreads();
  KWRITE(kvb0, kvb1, kvb2)
  KLOAD(kva0, kva1, kva2, 2)
  __syncthreads();
  QKMFMA(1)
  __syncthreads();
  KWRITE(kva0, kva1, kva2)
  VLOAD(kvb0, kvb1, kvb2, 0)  // V chunk 0 in flight under softmax
  __syncthreads();
  QKMFMA(2)

  // log2-domain softmax, normalization deferred to epilogue
  float inv[4];
  if (act) {
#pragma unroll
    for (int r = 0; r < 4; r++) {
      float m = -3e38f;
#pragma unroll
      for (int t = 0; t < 18; t++) m = fmaxf(m, s[t][r]);
      m = fmaxf(m, __shfl_xor(m, 1));
      m = fmaxf(m, __shfl_xor(m, 2));
      m = fmaxf(m, __shfl_xor(m, 4));
      m = fmaxf(m, __shfl_xor(m, 8));
      float sum = 0.f;
#pragma unroll
      for (int t = 0; t < 18; t++) {
        float p = __builtin_amdgcn_exp2f(s[t][r] - m);
        s[t][r] = p;
        sum += p;
      }
      sum += __shfl_xor(sum, 1);
      sum += __shfl_xor(sum, 2);
      sum += __shfl_xor(sum, 4);
      sum += __shfl_xor(sum, 8);
      inv[r] = 1.f / sum;
    }
  }

  // Phase 2: O = P.V^T-chunks (reg-prefetch pipelined; Pw wave-private)
  u16* Pw = Ps + wave * (16 * 104);
  f32x4 o[4];
#pragma unroll
  for (int nt = 0; nt < 4; nt++) o[nt] = (f32x4){0.f, 0.f, 0.f, 0.f};
  __syncthreads();
  VWRITE(kvb0, kvb1, kvb2)
  VLOAD(kva0, kva1, kva2, 1)
  PWRITE(0)
  __syncthreads();
  PVMFMA
  __syncthreads();
  VWRITE(kva0, kva1, kva2)
  VLOAD(kvb0, kvb1, kvb2, 2)
  PWRITE(1)
  __syncthreads();
  PVMFMA
  __syncthreads();
  VWRITE(kvb0, kvb1, kvb2)
  PWRITE(2)
  __syncthreads();
  PVMFMA

  // store O -> attn_out [B][257][H*64] bf16 (normalize here)
  if (act) {
#pragma unroll
    for (int nt = 0; nt < 4; nt++) {
      int d = nt * 16 + l15;
#pragma unroll
      for (int r = 0; r < 4; r++) {
        int qr = qbase + r;
        if (qr < 257)
          out[((size_t)b * 257 + qr) * 1024 + h * 64 + d] =
              f2bf(o[nt][r] * inv[r]);
      }
    }
  }
}

// ---------------- launch ----------------
extern "C" void kernel_launch(void* const* d_in, const int* in_sizes, int n_in,
                              void* d_out, int out_size, void* d_ws,
                              size_t ws_size, hipStream_t stream) {
  const float* x = (const float*)d_in[0];
  const float* qkvw = (const float*)d_in[1];
  const float* qb = (const float*)d_in[2];
  const float* vb = (const float*)d_in[3];
  const float* tab = (const float*)d_in[4];
  const float* pw = (const float*)d_in[5];
  const float* pb = (const float*)d_in[6];
  const int* rpi = (const int*)d_in[7];

  char* ws = (char*)d_ws;
  u16* qkvbuf = (u16*)ws;                    // q|k|v^T bf16, 101,974,016 B
  u16* xbuf = (u16*)(ws + 101974016);        // x bf16, reused as attn_out (33,685,504 B)
  u16* biasb = (u16*)(ws + 135659520);       // [16][257][288] bf16 *log2e, 2,368,512 B
  u16* qkvwb = (u16*)(ws + 139886656);       // 6,291,456 B
  u16* projwb = (u16*)(ws + 146178112);      // 2,097,152 B; end 148,275,264

  cvt_bf16<<<16448, 256, 0, stream>>>(x, xbuf, 4210688);
  cvt_bf16<<<3072, 256, 0, stream>>>(qkvw, qkvwb, 786432);
  cvt_bf16<<<1024, 256, 0, stream>>>(pw, projwb, 262144);
  bias_pre<<<290, 256, 0, stream>>>(tab, rpi, biasb);
  gemm_qkv<<<dim3(24, 129), 256, 0, stream>>>(xbuf, qkvwb, qb, vb, qkvbuf);
  attn_fused<<<5120, 256, 0, stream>>>(qkvbuf, biasb, xbuf);
  gemm_proj<<<dim3(8, 129), 256, 0, stream>>>(xbuf, projwb, pb, (float*)d_out);
}

// Round 11
// 405.483 us; speedup vs baseline: 1.0174x; 1.0174x over previous
//
#include <hip/hip_runtime.h>

// Pipeline: cvt(x,Wqkv,Wproj)->bf16 | bias_pre bf16 [16][257][288] pair-packed |
//           gemm_qkv (bf16 MFMA; q*(0.125*log2e)+qb, k, v+vb -> v^T layout) |
//           attn_fused (S=QK^T with bias-in-C, log2-softmax, O=PV, defer norm) |
//           gemm_proj (+proj_bias, fp32 out)
// R14 (retry; previous submission hit an infra failure — container acquisition,
// not a kernel error) = recombination of best measured pieces:
//   gemm_qkv : R8 core — BK=64, 32KB LDS, 2 barriers/iter (152.7us, R13).
//   gemm_proj: R12 core — BK=32 static double-buffer (B=2MB L2-resident ->
//              latency covered; ~-18us vs R8 core, attributed in R12).
//   attn     : R11/R12 loop version. R13's reg-prefetch REVERTED (+14us):
//              __syncthreads drains vmcnt(0) [m97 asm; R5 lesson], so loads
//              issued before a __syncthreads are waited immediately — no
//              hiding, plus 24 VGPR of dead buffers under (256,3).
// Kept: R7 v^T transpose epilogue; R8 tail-clamp removal; R11 bf16 bias
// pack + qt4 wave-0 gating + attn XCD relabel. GEMM XCD swizzle: falsified
// twice (LLC-resident) — absent.

typedef unsigned short u16;
typedef __attribute__((ext_vector_type(8))) short bf16x8;
typedef __attribute__((ext_vector_type(4))) float f32x4;

#define MFMA16(a, b, c) __builtin_amdgcn_mfma_f32_16x16x32_bf16(a, b, c, 0, 0, 0)
#define GLDS16(g, l)                                                           \
  __builtin_amdgcn_global_load_lds(                                            \
      (const __attribute__((address_space(1))) void*)(g),                      \
      (__attribute__((address_space(3))) void*)(l), 16, 0, 0)

// element offsets within qkv buffer
#define QOFF 0
#define KOFF 16842752
#define VTOFF 33685504
#define VTP 264  // v^T row pitch (elems), 528 B = 33*16

__device__ __forceinline__ u16 f2bf(float f) {
  unsigned u = __builtin_bit_cast(unsigned, f);
  u += 0x7FFFu + ((u >> 16) & 1u);  // RNE; inputs are finite
  return (u16)(u >> 16);
}
__device__ __forceinline__ unsigned pack2(float a, float b) {
  return (unsigned)f2bf(a) | ((unsigned)f2bf(b) << 16);
}

// ---------------- fp32 -> bf16 convert (vectorized) ----------------
__global__ __launch_bounds__(256) void cvt_bf16(const float* __restrict__ in,
                                                u16* __restrict__ out, int n4) {
  int i = blockIdx.x * 256 + threadIdx.x;
  if (i < n4) {
    float4 v = ((const float4*)in)[i];
    uint2 o;
    o.x = pack2(v.x, v.y);
    o.y = pack2(v.z, v.w);
    ((uint2*)out)[i] = o;
  }
}

// ---- bias precompute: bf16 [16][257][288] pair-interleaved (x log2e) ----
// entry (h,i,j) at h*74016 + i*288 + (j>>5)*32 + (j&15)*2 + ((j>>4)&1);
// cols 257..287 prefilled with bf16(-3e38) so the attn init needs no branch.
__global__ __launch_bounds__(256) void bias_pre(const float* __restrict__ tab,
                                                const int* __restrict__ idx,
                                                u16* __restrict__ out) {
  int t = blockIdx.x * 256 + threadIdx.x;
  if (t < 66049) {
    int i = t / 257, j = t - i * 257;
    int off = i * 288 + ((j >> 5) << 5) + ((j & 15) << 1) + ((j >> 4) & 1);
    int id = idx[t];
    const float* row = tab + (size_t)id * 16;
#pragma unroll
    for (int h = 0; h < 16; h++)
      out[(size_t)h * 74016 + off] = f2bf(row[h] * 1.4426950408889634f);
  } else if (t < 66049 + 257 * 31) {
    int u = t - 66049;
    int i = u / 31, j = 257 + (u - i * 31);
    int off = i * 288 + ((j >> 5) << 5) + ((j & 15) << 1) + ((j >> 4) & 1);
#pragma unroll
    for (int h = 0; h < 16; h++)
      out[(size_t)h * 74016 + off] = 0xFF7Fu;  // bf16 ~ -3.39e38
  }
}

// ---------------- GEMM core A: BK=64, 2 barriers/iter (for gemm_qkv) ----
// 128x128 tile, 256 thr (4 waves 2x2 of 64x64), 16x16x32 MFMA.
// LDS row = 64 elems (8 slots of 16B); k-group G of row r at slot G^(r&7).
#define GEMM_PROLOG64(M_, K_)                                                  \
  __shared__ __align__(16) u16 SMEM[16384];                                    \
  const int M = (M_), K = (K_);                                                \
  const int tid = threadIdx.x;                                                 \
  const int lane = tid & 63, wave = tid >> 6;                                  \
  const int quad = lane >> 4, l15 = lane & 15;                                 \
  const int wr = (wave >> 1) * 64, wc = (wave & 1) * 64;                       \
  const int m0 = blockIdx.y * 128, n0 = blockIdx.x * 128;                      \
  const int sgk = ((tid & 7) ^ ((tid >> 3) & 7)) * 8;                          \
  const int fo0 = (quad ^ (l15 & 7)) * 8;                                      \
  const int fo1 = ((4 + quad) ^ (l15 & 7)) * 8;                                \
  const u16* pa0 = A + (size_t)(m0 + (tid >> 3)) * K + sgk;                    \
  const u16* pb0 = B + (size_t)(n0 + (tid >> 3)) * K + sgk;                    \
  f32x4 acc[4][4];                                                             \
  _Pragma("unroll") for (int i = 0; i < 4; i++)                                \
  _Pragma("unroll") for (int j = 0; j < 4; j++)                                \
      acc[i][j] = (f32x4){0.f, 0.f, 0.f, 0.f};                                 \
  for (int k0 = 0; k0 < K; k0 += 64) {                                         \
    __syncthreads();                                                           \
    _Pragma("unroll") for (int b = 0; b < 4; b++) {                            \
      GLDS16(pa0 + k0 + (size_t)b * 32 * K, SMEM + b * 2048 + tid * 8);        \
      GLDS16(pb0 + k0 + (size_t)b * 32 * K, SMEM + 8192 + b * 2048 + tid * 8); \
    }                                                                          \
    __syncthreads();                                                           \
    _Pragma("unroll") for (int kk = 0; kk < 2; kk++) {                         \
      const int fo = kk ? fo1 : fo0;                                           \
      bf16x8 bfr[4];                                                           \
      _Pragma("unroll") for (int t = 0; t < 4; t++)                            \
          bfr[t] = *(const bf16x8*)(SMEM + 8192 + (wc + t * 16 + l15) * 64 + fo); \
      _Pragma("unroll") for (int i = 0; i < 4; i++) {                          \
        bf16x8 afr = *(const bf16x8*)(SMEM + (wr + i * 16 + l15) * 64 + fo);   \
        _Pragma("unroll") for (int j = 0; j < 4; j++)                          \
            acc[i][j] = MFMA16(afr, bfr[j], acc[i][j]);                        \
      }                                                                        \
    }                                                                          \
  }

// ---------------- GEMM core B: BK=32 static double-buffer (for gemm_proj) --
// LDS row = 32 elems; 16B-group g of row r at slot g^((r>>1)&3).
#define GSTAGE(BO, TI)                                                         \
  GLDS16(pa0 + (TI) * 32, SMEM + (BO) + tid * 8);                              \
  GLDS16(pa1 + (TI) * 32, SMEM + (BO) + 2048 + tid * 8);                       \
  GLDS16(pb0 + (TI) * 32, SMEM + (BO) + 4096 + tid * 8);                       \
  GLDS16(pb1 + (TI) * 32, SMEM + (BO) + 6144 + tid * 8);

#define GCOMPUTE(BO)                                                           \
  {                                                                            \
    const u16* As_ = SMEM + (BO);                                              \
    const u16* Bs_ = SMEM + (BO) + 4096;                                       \
    bf16x8 bfr[4];                                                             \
    _Pragma("unroll") for (int t = 0; t < 4; t++)                              \
        bfr[t] = *(const bf16x8*)(Bs_ + (wc + t * 16 + l15) * 32 + fo);        \
    _Pragma("unroll") for (int i = 0; i < 4; i++) {                            \
      bf16x8 afr = *(const bf16x8*)(As_ + (wr + i * 16 + l15) * 32 + fo);      \
      _Pragma("unroll") for (int j = 0; j < 4; j++)                            \
          acc[i][j] = MFMA16(afr, bfr[j], acc[i][j]);                          \
    }                                                                          \
  }

#define GEMM_PROLOG_DB(M_, K_)                                                 \
  __shared__ __align__(16) u16 SMEM[16384];                                    \
  const int M = (M_), K = (K_);                                                \
  const int tid = threadIdx.x;                                                 \
  const int lane = tid & 63, wave = tid >> 6;                                  \
  const int quad = lane >> 4, l15 = lane & 15;                                 \
  const int wr = (wave >> 1) * 64, wc = (wave & 1) * 64;                       \
  const int m0 = blockIdx.y * 128, n0 = blockIdx.x * 128;                      \
  const int sgk = (((tid & 3) ^ ((tid >> 3) & 3))) * 8;                        \
  const int fo = ((quad ^ ((l15 >> 1) & 3))) * 8;                              \
  const u16* pa0 = A + (size_t)(m0 + (tid >> 2)) * K + sgk;                    \
  const u16* pa1 = pa0 + (size_t)64 * K;                                       \
  const u16* pb0 = B + (size_t)(n0 + (tid >> 2)) * K + sgk;                    \
  const u16* pb1 = pb0 + (size_t)64 * K;                                       \
  f32x4 acc[4][4];                                                             \
  _Pragma("unroll") for (int i = 0; i < 4; i++)                                \
  _Pragma("unroll") for (int j = 0; j < 4; j++)                                \
      acc[i][j] = (f32x4){0.f, 0.f, 0.f, 0.f};                                 \
  GSTAGE(0, 0)                                                                 \
  __syncthreads();                                                             \
  for (int kt = 0; kt < 30; kt += 2) {                                         \
    GSTAGE(8192, kt + 1)                                                       \
    GCOMPUTE(0)                                                                \
    __syncthreads();                                                           \
    GSTAGE(0, kt + 2)                                                          \
    GCOMPUTE(8192)                                                             \
    __syncthreads();                                                           \
  }                                                                            \
  GSTAGE(8192, 31)                                                             \
  GCOMPUTE(0)                                                                  \
  __syncthreads();                                                             \
  GCOMPUTE(8192)

// QKV GEMM: cols [q|k|v]; q,k -> [B][H][257][64]; v -> v^T [B][H][64][VTP].
__global__ __launch_bounds__(256, 4) void gemm_qkv(
    const u16* __restrict__ A, const u16* __restrict__ B,
    const float* __restrict__ qbias, const float* __restrict__ vbias,
    u16* __restrict__ C) {
  GEMM_PROLOG64(16448, 1024)
  if (n0 >= 2048) {
    // ---- v-tile epilogue: transpose via LDS, stores coalesced along nn ----
    u16* const T = SMEM;  // [64 col][128 row] u16, row index XOR-swizzled
    for (int p = 0; p < 2; p++) {
      __syncthreads();
      if ((wave & 1) == p) {
#pragma unroll
        for (int j = 0; j < 4; j++) {
          int cl = j * 16 + l15;
          int rem = (n0 + wc + j * 16 + l15) & 1023;
          float vb_ = vbias[rem];
          int swz = (cl & 15) << 3;  // flips row bits 3..6, keeps pairs
#pragma unroll
          for (int i = 0; i < 4; i++) {
            int rlb = wr + i * 16 + quad * 4;  // even
#pragma unroll
            for (int rr = 0; rr < 2; rr++) {
              unsigned pk = pack2(acc[i][j][rr * 2] + vb_,
                                  acc[i][j][rr * 2 + 1] + vb_);
              *(unsigned*)(T + cl * 128 + ((rlb + rr * 2) ^ swz)) = pk;
            }
          }
        }
      }
      __syncthreads();
      // store: wave w covers cols {w, w+4, ..., w+60}; lanes run along rows
#pragma unroll
      for (int cc = 0; cc < 16; cc++) {
        int cl = cc * 4 + wave;
        int rem = (n0 + p * 64 + cl) & 1023;
        int h = rem >> 6, d = rem & 63;
        size_t cb = (size_t)VTOFF + ((size_t)h * 64 + d) * VTP;
        int swz = (cl & 15) << 3;
#pragma unroll
        for (int half = 0; half < 2; half++) {
          int rl = half * 64 + lane;
          u16 val = T[cl * 128 + (rl ^ swz)];
          int m = m0 + rl;
          if (m < M) {
            unsigned bb2 = (unsigned)m / 257u;
            unsigned nn2 = (unsigned)m - bb2 * 257u;
            C[cb + (size_t)bb2 * (16 * 64 * VTP) + nn2] = val;
          }
        }
      }
    }
  } else {
    // ---- q/k epilogue (coalesced along d already) ----
#pragma unroll
    for (int i = 0; i < 4; i++) {
#pragma unroll
      for (int r = 0; r < 4; r++) {
        int row = m0 + wr + i * 16 + quad * 4 + r;
        if (row < M) {
          unsigned bb = (unsigned)row / 257u;
          unsigned nn = (unsigned)row - bb * 257u;
#pragma unroll
          for (int j = 0; j < 4; j++) {
            int c = n0 + wc + j * 16 + l15;
            int which = c >> 10, rem = c & 1023;
            float bias = (which == 0) ? qbias[rem] : 0.f;
            float v = acc[i][j][r] + bias;
            if (which == 0) v *= 0.18033688011112042f;  // 64^-0.5 * log2(e)
            int h = rem >> 6, d = rem & 63;
            size_t dst = (size_t)which * 16842752 +
                         (size_t)(bb * 16 + h) * 16448 + (size_t)nn * 64 + d;
            C[dst] = f2bf(v);
          }
        }
      }
    }
  }
}

// Proj GEMM: fp32 out + proj_bias, row-major [16448][1024].
__global__ __launch_bounds__(256, 4) void gemm_proj(
    const u16* __restrict__ A, const u16* __restrict__ B,
    const float* __restrict__ pbias, float* __restrict__ C) {
  GEMM_PROLOG_DB(16448, 1024)
#pragma unroll
  for (int i = 0; i < 4; i++) {
#pragma unroll
    for (int r = 0; r < 4; r++) {
      int row = m0 + wr + i * 16 + quad * 4 + r;
      if (row < M) {
#pragma unroll
        for (int j = 0; j < 4; j++) {
          int c = n0 + wc + j * 16 + l15;
          C[(size_t)row * 1024 + c] = acc[i][j][r] + pbias[c];
        }
      }
    }
  }
}

// ---------------- fused attention ----------------
// grid = B*H*5; block = 4 waves; wave owns 16 q-rows. Keys padded 257->288.
// XCD relabel: the 5 q-tiles of one (b,h) land on one XCD (K/V L2-hot);
// each XCD sees only 2 distinct bias heads (L2-resident).
// qt=4 blocks have 1 valid row (cls): compute gated to wave 0; K/V staging
// and barriers stay unconditional (cls row still attends to all 257 keys).
__global__ __launch_bounds__(256, 3) void attn_fused(
    const u16* __restrict__ qkv, const u16* __restrict__ biasT,
    u16* __restrict__ out) {
  __shared__ __align__(16) u16 KVs[96 * 72];
  __shared__ __align__(16) u16 Ps[4 * 16 * 104];
  const int bx = blockIdx.x;
  const int xj = bx & 7, xi = bx >> 3;  // 640 per XCD
  const int qt = xi % 5;
  const int bh = (xi / 5) * 8 + xj;     // bijective: (xi/5, xj) <-> bh
  const int b = bh >> 4, h = bh & 15;
  const int tid = threadIdx.x, lane = tid & 63, wave = tid >> 6;
  const int quad = lane >> 4, l15 = lane & 15;
  const bool act = (qt < 4) || (wave == 0);  // wave-uniform compute gate
  const u16* qg = qkv + QOFF + (size_t)bh * 16448;
  const u16* kg = qkv + KOFF + (size_t)bh * 16448;
  const u16* vtg = qkv + VTOFF + (size_t)bh * (64 * VTP);

  // Q fragments straight from global (rows clamped for the tail tile)
  int qra = qt * 64 + wave * 16 + l15;
  if (qra > 256) qra = 256;
  const bf16x8 aq0 = *(const bf16x8*)(qg + (size_t)qra * 64 + quad * 8);
  const bf16x8 aq1 = *(const bf16x8*)(qg + (size_t)qra * 64 + 32 + quad * 8);

  // bias -> accumulator init (C-layout): bf16 pair-packed rows, pads = -3e38
  const int qbase = qt * 64 + wave * 16 + quad * 4;
  f32x4 s[18];
  if (act) {
    const u16* bb = biasT + (size_t)h * 74016;
#pragma unroll
    for (int r = 0; r < 4; r++) {
      int qr = qbase + r;
      if (qr > 256) qr = 256;
      const unsigned* brow = (const unsigned*)(bb + (size_t)qr * 288);
#pragma unroll
      for (int p = 0; p < 9; p++) {
        unsigned u = brow[p * 16 + l15];
        s[2 * p][r] = __builtin_bit_cast(float, u << 16);
        s[2 * p + 1][r] = __builtin_bit_cast(float, u & 0xFFFF0000u);
      }
    }
  }

  // Phase 1: S += Q.K^T over 3 key chunks of 96
  const bf16x8 zv = {0, 0, 0, 0, 0, 0, 0, 0};
  for (int ck = 0; ck < 3; ck++) {
    __syncthreads();
#pragma unroll
    for (int it = 0; it < 3; it++) {
      int g = it * 256 + tid;  // 768 groups of 8 elems
      int row = g >> 3, col = (g & 7) * 8;
      int gr = ck * 96 + row;
      bf16x8 kv = (gr < 257) ? *(const bf16x8*)(kg + (size_t)gr * 64 + col) : zv;
      *(bf16x8*)(KVs + row * 72 + col) = kv;
    }
    __syncthreads();
    if (act) {
#pragma unroll
      for (int nt = 0; nt < 6; nt++) {
        bf16x8 b0 = *(const bf16x8*)(KVs + (nt * 16 + l15) * 72 + quad * 8);
        bf16x8 b1 = *(const bf16x8*)(KVs + (nt * 16 + l15) * 72 + 32 + quad * 8);
        int t = ck * 6 + nt;
        s[t] = MFMA16(aq0, b0, s[t]);
        s[t] = MFMA16(aq1, b1, s[t]);
      }
    }
  }

  // log2-domain softmax, normalization deferred to epilogue
  float inv[4];
  if (act) {
#pragma unroll
    for (int r = 0; r < 4; r++) {
      float m = -3e38f;
#pragma unroll
      for (int t = 0; t < 18; t++) m = fmaxf(m, s[t][r]);
      m = fmaxf(m, __shfl_xor(m, 1));
      m = fmaxf(m, __shfl_xor(m, 2));
      m = fmaxf(m, __shfl_xor(m, 4));
      m = fmaxf(m, __shfl_xor(m, 8));
      float sum = 0.f;
#pragma unroll
      for (int t = 0; t < 18; t++) {
        float p = __builtin_amdgcn_exp2f(s[t][r] - m);
        s[t][r] = p;
        sum += p;
      }
      sum += __shfl_xor(sum, 1);
      sum += __shfl_xor(sum, 2);
      sum += __shfl_xor(sum, 4);
      sum += __shfl_xor(sum, 8);
      inv[r] = 1.f / sum;
    }
  }

  // Phase 2: O = P.V^T-chunks; P written per-chunk (wave-private Ps region)
  u16* Pw = Ps + wave * (16 * 104);
  f32x4 o[4];
#pragma unroll
  for (int nt = 0; nt < 4; nt++) o[nt] = (f32x4){0.f, 0.f, 0.f, 0.f};
  for (int ck = 0; ck < 3; ck++) {
    __syncthreads();
#pragma unroll
    for (int it = 0; it < 3; it++) {
      int g = it * 256 + tid;       // 768 groups: [64 d][12 col-groups]
      int row = g / 12, c = (g % 12) * 8;
      bf16x8 v = *(const bf16x8*)(vtg + (size_t)row * VTP + ck * 96 + c);
      *(bf16x8*)(KVs + row * 104 + c) = v;  // pad cols: finite garbage; P=0 there
    }
    if (act) {
#pragma unroll
      for (int nt = 0; nt < 6; nt++) {
        int t = ck * 6 + nt;
#pragma unroll
        for (int r = 0; r < 4; r++)
          Pw[(quad * 4 + r) * 104 + nt * 16 + l15] = f2bf(s[t][r]);
      }
    }
    __syncthreads();
    if (act) {
#pragma unroll
      for (int ks = 0; ks < 3; ks++) {
        bf16x8 ap = *(const bf16x8*)(Pw + l15 * 104 + ks * 32 + quad * 8);
#pragma unroll
        for (int nt = 0; nt < 4; nt++) {
          bf16x8 bv =
              *(const bf16x8*)(KVs + (nt * 16 + l15) * 104 + ks * 32 + quad * 8);
          o[nt] = MFMA16(ap, bv, o[nt]);
        }
      }
    }
  }

  // store O -> attn_out [B][257][H*64] bf16 (normalize here)
  if (act) {
#pragma unroll
    for (int nt = 0; nt < 4; nt++) {
      int d = nt * 16 + l15;
#pragma unroll
      for (int r = 0; r < 4; r++) {
        int qr = qbase + r;
        if (qr < 257)
          out[((size_t)b * 257 + qr) * 1024 + h * 64 + d] =
              f2bf(o[nt][r] * inv[r]);
      }
    }
  }
}

// ---------------- launch ----------------
extern "C" void kernel_launch(void* const* d_in, const int* in_sizes, int n_in,
                              void* d_out, int out_size, void* d_ws,
                              size_t ws_size, hipStream_t stream) {
  const float* x = (const float*)d_in[0];
  const float* qkvw = (const float*)d_in[1];
  const float* qb = (const float*)d_in[2];
  const float* vb = (const float*)d_in[3];
  const float* tab = (const float*)d_in[4];
  const float* pw = (const float*)d_in[5];
  const float* pb = (const float*)d_in[6];
  const int* rpi = (const int*)d_in[7];

  char* ws = (char*)d_ws;
  u16* qkvbuf = (u16*)ws;                    // q|k|v^T bf16, 101,974,016 B
  u16* xbuf = (u16*)(ws + 101974016);        // x bf16, reused as attn_out (33,685,504 B)
  u16* biasb = (u16*)(ws + 135659520);       // [16][257][288] bf16 *log2e, 2,368,512 B
  u16* qkvwb = (u16*)(ws + 139886656);       // 6,291,456 B
  u16* projwb = (u16*)(ws + 146178112);      // 2,097,152 B; end 148,275,264

  cvt_bf16<<<16448, 256, 0, stream>>>(x, xbuf, 4210688);
  cvt_bf16<<<3072, 256, 0, stream>>>(qkvw, qkvwb, 786432);
  cvt_bf16<<<1024, 256, 0, stream>>>(pw, projwb, 262144);
  bias_pre<<<290, 256, 0, stream>>>(tab, rpi, biasb);
  gemm_qkv<<<dim3(24, 129), 256, 0, stream>>>(xbuf, qkvwb, qb, vb, qkvbuf);
  attn_fused<<<5120, 256, 0, stream>>>(qkvbuf, biasb, xbuf);
  gemm_proj<<<dim3(8, 129), 256, 0, stream>>>(xbuf, projwb, pb, (float*)d_out);
}